// Round 7
// baseline (463.248 us; speedup 1.0000x reference)
//
#include <hip/hip_runtime.h>
#include <hip/hip_bf16.h>
#include <math.h>

typedef __attribute__((ext_vector_type(4))) float f32x4;
typedef __attribute__((ext_vector_type(8))) short short8;

#define NN 8192
#define LOG2E 1.44269504088896f

// f32 -> bf16 bits, round-to-nearest-even
__device__ __forceinline__ short f2bf(float x) {
    unsigned u = __float_as_uint(x);
    u += 0x7FFFu + ((u >> 16) & 1u);
    return (short)(u >> 16);
}
__device__ __forceinline__ float expneg(float s) {   // exp(-s)
    return __builtin_amdgcn_exp2f(-LOG2E * s);
}

// ---------------------------------------------------------------------------
// P1: h = x @ W1  [8192,500]@[500,64] with W1 staged in LDS.
// Writes fsrc = exp(-h.a_src), edst = exp(-h.a_dst).
// ---------------------------------------------------------------------------
#define P1_CHUNK 100
__global__ __launch_bounds__(256) void p1_kernel(
    const float* __restrict__ x, const float* __restrict__ W1,
    const float* __restrict__ a1, float* __restrict__ h,
    float* __restrict__ fsrc, float* __restrict__ edst)
{
    __shared__ float wtile[P1_CHUNK * 64];
    const int lane = threadIdx.x & 63;
    const int w    = threadIdx.x >> 6;
    const int r0   = blockIdx.x * 32 + w * 8;

    float acc[8];
#pragma unroll
    for (int r = 0; r < 8; ++r) acc[r] = 0.f;

    for (int c = 0; c < 5; ++c) {
        const int kb = c * P1_CHUNK;
        __syncthreads();
        for (int idx = threadIdx.x; idx < P1_CHUNK * 64; idx += 256)
            wtile[idx] = W1[kb * 64 + idx];
        __syncthreads();
        for (int kk = 0; kk < P1_CHUNK; kk += 4) {
            float w0 = wtile[(kk + 0) * 64 + lane];
            float w1 = wtile[(kk + 1) * 64 + lane];
            float w2 = wtile[(kk + 2) * 64 + lane];
            float w3 = wtile[(kk + 3) * 64 + lane];
#pragma unroll
            for (int r = 0; r < 8; ++r) {
                f32x4 xv = *(const f32x4*)(x + (size_t)(r0 + r) * 500 + kb + kk);
                acc[r] = fmaf(xv[0], w0, acc[r]);
                acc[r] = fmaf(xv[1], w1, acc[r]);
                acc[r] = fmaf(xv[2], w2, acc[r]);
                acc[r] = fmaf(xv[3], w3, acc[r]);
            }
        }
    }
    float a_s = a1[lane], a_d = a1[64 + lane];
#pragma unroll
    for (int r = 0; r < 8; ++r) {
        h[(size_t)(r0 + r) * 64 + lane] = acc[r];
        float ps = acc[r] * a_s, pd = acc[r] * a_d;
        for (int off = 32; off > 0; off >>= 1) {
            ps += __shfl_down(ps, off); pd += __shfl_down(pd, off);
        }
        if (lane == 0) {
            fsrc[r0 + r] = expneg(ps);
            edst[r0 + r] = expneg(pd);
        }
    }
}

// ---------------------------------------------------------------------------
// Swizzle f32 matrix into bf16 B-fragment order:
// hB[kb][nb][lane][i] = bf16( h[kb*32 + (lane>>4)*8 + i][nb*16 + (lane&15)] )
// ---------------------------------------------------------------------------
__global__ __launch_bounds__(256) void swizzle_kernel(
    const float* __restrict__ h, short* __restrict__ hB,
    int nblk, int ncols, int total)
{
    int tid = blockIdx.x * 256 + threadIdx.x;
    if (tid >= total) return;
    int i  = tid & 7;
    int l  = (tid >> 3) & 63;
    int t2 = tid >> 9;
    int nb = t2 % nblk;
    int kb = t2 / nblk;
    int row = kb * 32 + (l >> 4) * 8 + i;
    int col = nb * 16 + (l & 15);
    hB[tid] = f2bf(h[(size_t)row * ncols + col]);
}

// ---------------------------------------------------------------------------
// att_kernel: PURE STREAMING. att = adj * rcp(1 + F_i * E_j), written as bf16
// in MFMA A-fragment order: attB[mb][kb][lane=(r&15)+16*g][j] =
// att[mb*16+(r&15)][kb*32+g*8+j]. Also per-row sum(att^2) -> normp[half][row].
// Block = 16 rows x 4096 cols; per-thread f32x8 lane-contiguous loads
// (copy-benchmark pattern); depth-1 row prefetch; NO LDS/MFMA/sync in loop.
// Grid (512, 2) = 1024 blocks.
// ---------------------------------------------------------------------------
__global__ __launch_bounds__(256) void att_kernel(
    const float* __restrict__ adj, const float* __restrict__ fsrc,
    const float* __restrict__ edst, short* __restrict__ attB,
    float* __restrict__ normp)
{
    __shared__ float nlds[4][16][64];   // [wave][row][lane]
    __shared__ float red2[16][16];
    const int tid  = threadIdx.x;
    const int lane = tid & 63;
    const int w    = tid >> 6;
    const int rb   = blockIdx.x;
    const int half = blockIdx.y;
    const int c0   = half * 4096;

    // E_j for this thread's 16 columns, kept in registers
    f32x4 e[2][2];
#pragma unroll
    for (int i = 0; i < 2; ++i) {
        e[i][0] = *(const f32x4*)(edst + c0 + i * 2048 + tid * 8);
        e[i][1] = *(const f32x4*)(edst + c0 + i * 2048 + tid * 8 + 4);
    }

    f32x4 ac[2][2], an[2][2];
    {
        const float* arow = adj + (size_t)(rb * 16) * NN + c0 + tid * 8;
#pragma unroll
        for (int i = 0; i < 2; ++i) {
            ac[i][0] = *(const f32x4*)(arow + i * 2048);
            ac[i][1] = *(const f32x4*)(arow + i * 2048 + 4);
        }
    }

    for (int r = 0; r < 16; ++r) {
        if (r < 15) {
            const float* arow = adj + (size_t)(rb * 16 + r + 1) * NN + c0 + tid * 8;
#pragma unroll
            for (int i = 0; i < 2; ++i) {
                an[i][0] = *(const f32x4*)(arow + i * 2048);
                an[i][1] = *(const f32x4*)(arow + i * 2048 + 4);
            }
        }
        const float F_i = fsrc[rb * 16 + r];
        float nacc = 0.f;
#pragma unroll
        for (int i = 0; i < 2; ++i) {
            short8 af;
#pragma unroll
            for (int t = 0; t < 4; ++t) {
                float sg  = __builtin_amdgcn_rcpf(fmaf(F_i, e[i][0][t], 1.0f));
                float att = sg * ac[i][0][t];
                nacc = fmaf(att, att, nacc);
                af[t] = f2bf(att);
            }
#pragma unroll
            for (int t = 0; t < 4; ++t) {
                float sg  = __builtin_amdgcn_rcpf(fmaf(F_i, e[i][1][t], 1.0f));
                float att = sg * ac[i][1][t];
                nacc = fmaf(att, att, nacc);
                af[4 + t] = f2bf(att);
            }
            const int col = c0 + i * 2048 + tid * 8;
            const int kb  = col >> 5;
            const int g   = (col >> 3) & 3;
            *(short8*)(attB + (((size_t)rb * 256 + kb) * 64 + r + 16 * g) * 8) = af;
        }
        nlds[w][r][lane] = nacc;
#pragma unroll
        for (int i = 0; i < 2; ++i) {
            ac[i][0] = an[i][0];
            ac[i][1] = an[i][1];
        }
    }
    __syncthreads();
    {
        const int r = tid >> 4;
        const int c = tid & 15;
        float s = 0.f;
#pragma unroll
        for (int w2 = 0; w2 < 4; ++w2)
#pragma unroll
            for (int p = 0; p < 4; ++p)
                s += nlds[w2][r][c + 16 * p];
        red2[r][c] = s;
    }
    __syncthreads();
    if (tid < 16) {
        float s = 0.f;
#pragma unroll
        for (int c = 0; c < 16; ++c) s += red2[tid][c];
        normp[half * NN + rb * 16 + tid] = s;
    }
}

// ---------------------------------------------------------------------------
// Skinny GEMM: C_partial[seg] = attB[:, seg-cols] @ Bfrag[seg].
// A-fragments are CONTIGUOUS short8 loads (1 KB/wave) from the fragment-
// ordered attB; B-slice staged in LDS once; depth-4 A register prefetch;
// nothing else in the VMEM FIFO. Block = 8 waves x 16 rows = 128 rows.
// Grid (64, 16).
// ---------------------------------------------------------------------------
template <int NBLK>
__global__ __launch_bounds__(512) void gemm_kernel(
    const short* __restrict__ A, const short* __restrict__ Bfrag,
    float* __restrict__ outp)
{
    __shared__ __align__(16) short Bs[16 * NBLK * 64 * 8];
    const int tid  = threadIdx.x;
    const int lane = tid & 63;
    const int w    = tid >> 6;
    const int seg  = blockIdx.y;
    const int mb   = blockIdx.x * 8 + w;
    const int r    = lane & 15;
    const int g    = lane >> 4;

    {
        const short8* src = (const short8*)(Bfrag) + (size_t)seg * (16 * NBLK * 64);
        short8* dst = (short8*)Bs;
#pragma unroll
        for (int j = 0; j < 2 * NBLK; ++j)
            dst[tid + 512 * j] = src[tid + 512 * j];
    }
    __syncthreads();

    const short8* Ap = (const short8*)(A) + ((size_t)mb * 256 + seg * 16) * 64 + lane;

    f32x4 acc[NBLK];
#pragma unroll
    for (int nb = 0; nb < NBLK; ++nb) acc[nb] = (f32x4){0.f, 0.f, 0.f, 0.f};

    auto compute = [&](int k, short8 av) {
#pragma unroll
        for (int nb = 0; nb < NBLK; ++nb) {
            short8 bf = *(const short8*)&Bs[((k * NBLK + nb) * 64 + lane) * 8];
            acc[nb] = __builtin_amdgcn_mfma_f32_16x16x32_bf16(av, bf, acc[nb], 0, 0, 0);
        }
    };

    short8 A0 = Ap[0 * 64], A1 = Ap[1 * 64], A2 = Ap[2 * 64], A3 = Ap[3 * 64];
#pragma unroll
    for (int k = 0; k < 16; k += 4) {
        short8 N0 = A0, N1 = A1, N2 = A2, N3 = A3;
        if (k + 4 < 16) {
            N0 = Ap[(k + 4) * 64]; N1 = Ap[(k + 5) * 64];
            N2 = Ap[(k + 6) * 64]; N3 = Ap[(k + 7) * 64];
        }
        compute(k + 0, A0);
        compute(k + 1, A1);
        compute(k + 2, A2);
        compute(k + 3, A3);
        A0 = N0; A1 = N1; A2 = N2; A3 = N3;
    }

    const int F = NBLK * 16;
#pragma unroll
    for (int nb = 0; nb < NBLK; ++nb)
#pragma unroll
        for (int rr = 0; rr < 4; ++rr)
            outp[((size_t)seg * NN + mb * 16 + g * 4 + rr) * F + nb * 16 + r]
                = acc[nb][rr];
}

// ---------------------------------------------------------------------------
// R1: h1[i][f] = sum_seg outp1 / (sqrt(normp_half0+half1) + 1e-10)
// ---------------------------------------------------------------------------
__global__ __launch_bounds__(256) void r1_kernel(
    const float* __restrict__ outp, const float* __restrict__ normp,
    float* __restrict__ h1)
{
    int tid = blockIdx.x * 256 + threadIdx.x;
    int i = tid >> 6, f = tid & 63;
    float s = 0.f;
#pragma unroll
    for (int sg = 0; sg < 16; ++sg)
        s += outp[((size_t)sg * NN + i) * 64 + f];
    float n = normp[i] + normp[NN + i];
    h1[tid] = s / (sqrtf(n) + 1e-10f);
}

// ---------------------------------------------------------------------------
// P2: z = h1 @ W2 (padded to 16 cols), fsrc2/edst2 = exp(-z . a2 halves)
// ---------------------------------------------------------------------------
__global__ __launch_bounds__(256) void p2_kernel(
    const float* __restrict__ h1, const float* __restrict__ W2,
    const float* __restrict__ a2, float* __restrict__ z,
    float* __restrict__ fsrc2, float* __restrict__ edst2)
{
    int i = blockIdx.x * 256 + threadIdx.x;
    if (i >= NN) return;
    float zz[10];
#pragma unroll
    for (int c = 0; c < 10; ++c) zz[c] = 0.f;
    for (int f = 0; f < 64; ++f) {
        float hv = h1[(size_t)i * 64 + f];
#pragma unroll
        for (int c = 0; c < 10; ++c) zz[c] = fmaf(hv, W2[f * 10 + c], zz[c]);
    }
    float s1 = 0.f, s2 = 0.f;
#pragma unroll
    for (int c = 0; c < 10; ++c) {
        s1 = fmaf(zz[c], a2[c], s1);
        s2 = fmaf(zz[c], a2[10 + c], s2);
        z[(size_t)i * 16 + c] = zz[c];
    }
#pragma unroll
    for (int c = 10; c < 16; ++c) z[(size_t)i * 16 + c] = 0.f;
    fsrc2[i] = expneg(s1);
    edst2[i] = expneg(s2);
}

// ---------------------------------------------------------------------------
// R2: h2 = partials/norm, then log_softmax over 10 classes -> d_out
// ---------------------------------------------------------------------------
__global__ __launch_bounds__(256) void r2_kernel(
    const float* __restrict__ outp, const float* __restrict__ normp,
    float* __restrict__ out)
{
    int i = blockIdx.x * 256 + threadIdx.x;
    if (i >= NN) return;
    float n = normp[i] + normp[NN + i];
    float inv = 1.0f / (sqrtf(n) + 1e-10f);
    float v[10];
    float m = -1e30f;
#pragma unroll
    for (int c = 0; c < 10; ++c) {
        float s = 0.f;
#pragma unroll
        for (int sg = 0; sg < 16; ++sg)
            s += outp[((size_t)sg * NN + i) * 16 + c];
        v[c] = s * inv;
        m = fmaxf(m, v[c]);
    }
    float es = 0.f;
#pragma unroll
    for (int c = 0; c < 10; ++c) es += expf(v[c] - m);
    float lse = m + logf(es);
#pragma unroll
    for (int c = 0; c < 10; ++c) out[(size_t)i * 10 + c] = v[c] - lse;
}

extern "C" void kernel_launch(void* const* d_in, const int* in_sizes, int n_in,
                              void* d_out, int out_size, void* d_ws, size_t ws_size,
                              hipStream_t stream)
{
    const float* x   = (const float*)d_in[0];
    const float* adj = (const float*)d_in[1];
    const float* W1  = (const float*)d_in[2];
    const float* a1  = (const float*)d_in[3];
    const float* W2  = (const float*)d_in[4];
    const float* a2  = (const float*)d_in[5];
    float* out = (float*)d_out;

    char* ws = (char*)d_ws;
    size_t off = 0;
    auto alloc = [&](size_t bytes) -> void* {
        void* p = ws + off;
        off += (bytes + 255) & ~(size_t)255;
        return p;
    };
    short* attB   = (short*)alloc((size_t)NN * NN * 2);          // 134MB (reused layer 2)
    float* h      = (float*)alloc((size_t)NN * 64 * 4);
    float* fsrc1  = (float*)alloc((size_t)NN * 4);
    float* edst1  = (float*)alloc((size_t)NN * 4);
    short* hB1    = (short*)alloc((size_t)NN * 64 * 2);
    float* outp1  = (float*)alloc((size_t)16 * NN * 64 * 4);     // 33.5MB
    float* normp1 = (float*)alloc((size_t)2 * NN * 4);
    float* h1     = (float*)alloc((size_t)NN * 64 * 4);
    float* z      = (float*)alloc((size_t)NN * 16 * 4);
    float* fsrc2  = (float*)alloc((size_t)NN * 4);
    float* edst2  = (float*)alloc((size_t)NN * 4);
    short* zB     = (short*)alloc((size_t)NN * 16 * 2);
    float* outp2  = (float*)alloc((size_t)16 * NN * 16 * 4);     // 8.4MB
    float* normp2 = (float*)alloc((size_t)2 * NN * 4);

    hipLaunchKernelGGL(p1_kernel, dim3(NN / 32), dim3(256), 0, stream,
                       x, W1, a1, h, fsrc1, edst1);
    hipLaunchKernelGGL(swizzle_kernel, dim3(2048), dim3(256), 0, stream,
                       h, hB1, 4, 64, NN * 64);
    hipLaunchKernelGGL(att_kernel, dim3(NN / 16, 2), dim3(256), 0, stream,
                       adj, fsrc1, edst1, attB, normp1);
    hipLaunchKernelGGL((gemm_kernel<4>), dim3(64, 16), dim3(512), 0, stream,
                       attB, hB1, outp1);
    hipLaunchKernelGGL(r1_kernel, dim3(2048), dim3(256), 0, stream,
                       outp1, normp1, h1);
    hipLaunchKernelGGL(p2_kernel, dim3(32), dim3(256), 0, stream,
                       h1, W2, a2, z, fsrc2, edst2);
    hipLaunchKernelGGL(swizzle_kernel, dim3(512), dim3(256), 0, stream,
                       z, zB, 1, 16, NN * 16);
    hipLaunchKernelGGL(att_kernel, dim3(NN / 16, 2), dim3(256), 0, stream,
                       adj, fsrc2, edst2, attB, normp2);
    hipLaunchKernelGGL((gemm_kernel<1>), dim3(64, 16), dim3(512), 0, stream,
                       attB, zB, outp2);
    hipLaunchKernelGGL(r2_kernel, dim3(32), dim3(256), 0, stream,
                       outp2, normp2, out);
}

// Round 8
// 429.856 us; speedup vs baseline: 1.0777x; 1.0777x over previous
//
#include <hip/hip_runtime.h>
#include <hip/hip_bf16.h>
#include <math.h>

typedef __attribute__((ext_vector_type(4))) float f32x4;
typedef __attribute__((ext_vector_type(8))) short short8;

#define NN 8192
#define LOG2E 1.44269504088896f
#define ATT_BLOCKS 2048

// f32 -> bf16 bits, round-to-nearest-even
__device__ __forceinline__ short f2bf(float x) {
    unsigned u = __float_as_uint(x);
    u += 0x7FFFu + ((u >> 16) & 1u);
    return (short)(u >> 16);
}
__device__ __forceinline__ float expneg(float s) {   // exp(-s)
    return __builtin_amdgcn_exp2f(-LOG2E * s);
}

// ---------------------------------------------------------------------------
// P1: h = x @ W1  [8192,500]@[500,64] with W1 staged in LDS. 512 blocks x
// 16 rows (4 rows/wave) for 8 waves/CU. Writes fsrc/edst = exp(-h.a halves).
// ---------------------------------------------------------------------------
#define P1_CHUNK 100
__global__ __launch_bounds__(256) void p1_kernel(
    const float* __restrict__ x, const float* __restrict__ W1,
    const float* __restrict__ a1, float* __restrict__ h,
    float* __restrict__ fsrc, float* __restrict__ edst)
{
    __shared__ float wtile[P1_CHUNK * 64];
    const int lane = threadIdx.x & 63;
    const int w    = threadIdx.x >> 6;
    const int r0   = blockIdx.x * 16 + w * 4;

    float acc[4];
#pragma unroll
    for (int r = 0; r < 4; ++r) acc[r] = 0.f;

    for (int c = 0; c < 5; ++c) {
        const int kb = c * P1_CHUNK;
        __syncthreads();
        for (int idx = threadIdx.x; idx < P1_CHUNK * 64; idx += 256)
            wtile[idx] = W1[kb * 64 + idx];
        __syncthreads();
        for (int kk = 0; kk < P1_CHUNK; kk += 4) {
            float w0 = wtile[(kk + 0) * 64 + lane];
            float w1 = wtile[(kk + 1) * 64 + lane];
            float w2 = wtile[(kk + 2) * 64 + lane];
            float w3 = wtile[(kk + 3) * 64 + lane];
#pragma unroll
            for (int r = 0; r < 4; ++r) {
                f32x4 xv = *(const f32x4*)(x + (size_t)(r0 + r) * 500 + kb + kk);
                acc[r] = fmaf(xv[0], w0, acc[r]);
                acc[r] = fmaf(xv[1], w1, acc[r]);
                acc[r] = fmaf(xv[2], w2, acc[r]);
                acc[r] = fmaf(xv[3], w3, acc[r]);
            }
        }
    }
    float a_s = a1[lane], a_d = a1[64 + lane];
#pragma unroll
    for (int r = 0; r < 4; ++r) {
        h[(size_t)(r0 + r) * 64 + lane] = acc[r];
        float ps = acc[r] * a_s, pd = acc[r] * a_d;
        for (int off = 32; off > 0; off >>= 1) {
            ps += __shfl_down(ps, off); pd += __shfl_down(pd, off);
        }
        if (lane == 0) {
            fsrc[r0 + r] = expneg(ps);
            edst[r0 + r] = expneg(pd);
        }
    }
}

// ---------------------------------------------------------------------------
// Swizzle f32 matrix into bf16 B-fragment order:
// hB[kb][nb][lane][i] = bf16( h[kb*32 + (lane>>4)*8 + i][nb*16 + (lane&15)] )
// ---------------------------------------------------------------------------
__global__ __launch_bounds__(256) void swizzle_kernel(
    const float* __restrict__ h, short* __restrict__ hB,
    int nblk, int ncols, int total)
{
    int tid = blockIdx.x * 256 + threadIdx.x;
    if (tid >= total) return;
    int i  = tid & 7;
    int l  = (tid >> 3) & 63;
    int t2 = tid >> 9;
    int nb = t2 % nblk;
    int kb = t2 / nblk;
    int row = kb * 32 + (l >> 4) * 8 + i;
    int col = nb * 16 + (l & 15);
    hB[tid] = f2bf(h[(size_t)row * ncols + col]);
}

// ---------------------------------------------------------------------------
// att_kernel: PURE TLP streaming. One thread = 8 consecutive cols of one row:
// 2 dwordx4 adj loads, ~50 VALU, one 16B store in MFMA A-fragment order,
// wave shuffle-reduce -> normpart[row][16]. No LDS, no barriers, ~30 VGPR ->
// 32 waves/CU at 2048 blocks x 16 grid-stride iterations.
// ---------------------------------------------------------------------------
__global__ __launch_bounds__(256) void att_kernel(
    const float* __restrict__ adj, const float* __restrict__ fsrc,
    const float* __restrict__ edst, short* __restrict__ attB,
    float* __restrict__ normpart)
{
    const int tid  = threadIdx.x;
    const int bid  = blockIdx.x;
    const int lane = tid & 63;
    const int NIT  = (NN / 8) * NN / (ATT_BLOCKS * 256);   // 16
    for (int it = 0; it < NIT; ++it) {
        const int gtid = (it * ATT_BLOCKS + bid) * 256 + tid;
        const int row  = gtid >> 10;          // 1024 8-col chunks per row
        const int c8   = gtid & 1023;
        const int col0 = c8 * 8;
        const float* ap = adj + (size_t)row * NN + col0;
        f32x4 a0 = *(const f32x4*)(ap);
        f32x4 a1 = *(const f32x4*)(ap + 4);
        f32x4 e0 = *(const f32x4*)(edst + col0);
        f32x4 e1 = *(const f32x4*)(edst + col0 + 4);
        const float F_i = fsrc[row];
        float nacc = 0.f;
        short8 af;
#pragma unroll
        for (int t = 0; t < 4; ++t) {
            float sg  = __builtin_amdgcn_rcpf(fmaf(F_i, e0[t], 1.0f));
            float att = sg * a0[t];
            nacc = fmaf(att, att, nacc);
            af[t] = f2bf(att);
        }
#pragma unroll
        for (int t = 0; t < 4; ++t) {
            float sg  = __builtin_amdgcn_rcpf(fmaf(F_i, e1[t], 1.0f));
            float att = sg * a1[t];
            nacc = fmaf(att, att, nacc);
            af[4 + t] = f2bf(att);
        }
        // A-fragment order: lane = (row&15) + 16*((col>>3)&3), kb = col>>5
        const int mb = row >> 4, r = row & 15;
        const int kb = col0 >> 5, g = (col0 >> 3) & 3;
        *(short8*)(attB + (((size_t)mb * 256 + kb) * 64 + g * 16 + r) * 8) = af;
        // wave covers 512 consecutive cols of ONE row -> wave reduce
        nacc += __shfl_down(nacc, 32);
        nacc += __shfl_down(nacc, 16);
        nacc += __shfl_down(nacc, 8);
        nacc += __shfl_down(nacc, 4);
        nacc += __shfl_down(nacc, 2);
        nacc += __shfl_down(nacc, 1);
        if (lane == 0) normpart[row * 16 + (c8 >> 6)] = nacc;
    }
}

// ---------------------------------------------------------------------------
// Skinny GEMM: C_partial[seg] = attB[:, seg-cols] @ Bfrag[seg].
// A-fragments are CONTIGUOUS short8 loads from fragment-ordered attB;
// B-slice staged in LDS once; depth-4 A register prefetch.
// Block = 8 waves x 16 rows = 128 rows. Grid (64, 16).
// ---------------------------------------------------------------------------
template <int NBLK>
__global__ __launch_bounds__(512) void gemm_kernel(
    const short* __restrict__ A, const short* __restrict__ Bfrag,
    float* __restrict__ outp)
{
    __shared__ __align__(16) short Bs[16 * NBLK * 64 * 8];
    const int tid  = threadIdx.x;
    const int lane = tid & 63;
    const int w    = tid >> 6;
    const int seg  = blockIdx.y;
    const int mb   = blockIdx.x * 8 + w;
    const int r    = lane & 15;
    const int g    = lane >> 4;

    {
        const short8* src = (const short8*)(Bfrag) + (size_t)seg * (16 * NBLK * 64);
        short8* dst = (short8*)Bs;
#pragma unroll
        for (int j = 0; j < 2 * NBLK; ++j)
            dst[tid + 512 * j] = src[tid + 512 * j];
    }
    __syncthreads();

    const short8* Ap = (const short8*)(A) + ((size_t)mb * 256 + seg * 16) * 64 + lane;

    f32x4 acc[NBLK];
#pragma unroll
    for (int nb = 0; nb < NBLK; ++nb) acc[nb] = (f32x4){0.f, 0.f, 0.f, 0.f};

    auto compute = [&](int k, short8 av) {
#pragma unroll
        for (int nb = 0; nb < NBLK; ++nb) {
            short8 bf = *(const short8*)&Bs[((k * NBLK + nb) * 64 + lane) * 8];
            acc[nb] = __builtin_amdgcn_mfma_f32_16x16x32_bf16(av, bf, acc[nb], 0, 0, 0);
        }
    };

    short8 A0 = Ap[0 * 64], A1 = Ap[1 * 64], A2 = Ap[2 * 64], A3 = Ap[3 * 64];
#pragma unroll
    for (int k = 0; k < 16; k += 4) {
        short8 N0 = A0, N1 = A1, N2 = A2, N3 = A3;
        if (k + 4 < 16) {
            N0 = Ap[(k + 4) * 64]; N1 = Ap[(k + 5) * 64];
            N2 = Ap[(k + 6) * 64]; N3 = Ap[(k + 7) * 64];
        }
        compute(k + 0, A0);
        compute(k + 1, A1);
        compute(k + 2, A2);
        compute(k + 3, A3);
        A0 = N0; A1 = N1; A2 = N2; A3 = N3;
    }

    const int F = NBLK * 16;
#pragma unroll
    for (int nb = 0; nb < NBLK; ++nb)
#pragma unroll
        for (int rr = 0; rr < 4; ++rr)
            outp[((size_t)seg * NN + mb * 16 + g * 4 + rr) * F + nb * 16 + r]
                = acc[nb][rr];
}

// ---------------------------------------------------------------------------
// R1: h1[i][f] = sum_seg outp1 / (sqrt(sum_p normpart1[i][p]) + 1e-10)
// ---------------------------------------------------------------------------
__global__ __launch_bounds__(256) void r1_kernel(
    const float* __restrict__ outp, const float* __restrict__ normpart,
    float* __restrict__ h1)
{
    int tid = blockIdx.x * 256 + threadIdx.x;
    int i = tid >> 6, f = tid & 63;
    float s = 0.f;
#pragma unroll
    for (int sg = 0; sg < 16; ++sg)
        s += outp[((size_t)sg * NN + i) * 64 + f];
    float n = 0.f;
#pragma unroll
    for (int p = 0; p < 16; ++p) n += normpart[i * 16 + p];
    h1[tid] = s / (sqrtf(n) + 1e-10f);
}

// ---------------------------------------------------------------------------
// P2: z = h1 @ W2 (padded to 16 cols), fsrc2/edst2 = exp(-z . a2 halves)
// ---------------------------------------------------------------------------
__global__ __launch_bounds__(256) void p2_kernel(
    const float* __restrict__ h1, const float* __restrict__ W2,
    const float* __restrict__ a2, float* __restrict__ z,
    float* __restrict__ fsrc2, float* __restrict__ edst2)
{
    int i = blockIdx.x * 256 + threadIdx.x;
    if (i >= NN) return;
    float zz[10];
#pragma unroll
    for (int c = 0; c < 10; ++c) zz[c] = 0.f;
    for (int f = 0; f < 64; ++f) {
        float hv = h1[(size_t)i * 64 + f];
#pragma unroll
        for (int c = 0; c < 10; ++c) zz[c] = fmaf(hv, W2[f * 10 + c], zz[c]);
    }
    float s1 = 0.f, s2 = 0.f;
#pragma unroll
    for (int c = 0; c < 10; ++c) {
        s1 = fmaf(zz[c], a2[c], s1);
        s2 = fmaf(zz[c], a2[10 + c], s2);
        z[(size_t)i * 16 + c] = zz[c];
    }
#pragma unroll
    for (int c = 10; c < 16; ++c) z[(size_t)i * 16 + c] = 0.f;
    fsrc2[i] = expneg(s1);
    edst2[i] = expneg(s2);
}

// ---------------------------------------------------------------------------
// R2: h2 = partials/norm, then log_softmax over 10 classes -> d_out
// ---------------------------------------------------------------------------
__global__ __launch_bounds__(256) void r2_kernel(
    const float* __restrict__ outp, const float* __restrict__ normpart,
    float* __restrict__ out)
{
    int i = blockIdx.x * 256 + threadIdx.x;
    if (i >= NN) return;
    float n = 0.f;
#pragma unroll
    for (int p = 0; p < 16; ++p) n += normpart[i * 16 + p];
    float inv = 1.0f / (sqrtf(n) + 1e-10f);
    float v[10];
    float m = -1e30f;
#pragma unroll
    for (int c = 0; c < 10; ++c) {
        float s = 0.f;
#pragma unroll
        for (int sg = 0; sg < 16; ++sg)
            s += outp[((size_t)sg * NN + i) * 16 + c];
        v[c] = s * inv;
        m = fmaxf(m, v[c]);
    }
    float es = 0.f;
#pragma unroll
    for (int c = 0; c < 10; ++c) es += expf(v[c] - m);
    float lse = m + logf(es);
#pragma unroll
    for (int c = 0; c < 10; ++c) out[(size_t)i * 10 + c] = v[c] - lse;
}

extern "C" void kernel_launch(void* const* d_in, const int* in_sizes, int n_in,
                              void* d_out, int out_size, void* d_ws, size_t ws_size,
                              hipStream_t stream)
{
    const float* x   = (const float*)d_in[0];
    const float* adj = (const float*)d_in[1];
    const float* W1  = (const float*)d_in[2];
    const float* a1  = (const float*)d_in[3];
    const float* W2  = (const float*)d_in[4];
    const float* a2  = (const float*)d_in[5];
    float* out = (float*)d_out;

    char* ws = (char*)d_ws;
    size_t off = 0;
    auto alloc = [&](size_t bytes) -> void* {
        void* p = ws + off;
        off += (bytes + 255) & ~(size_t)255;
        return p;
    };
    short* attB   = (short*)alloc((size_t)NN * NN * 2);          // 134MB (reused layer 2)
    float* h      = (float*)alloc((size_t)NN * 64 * 4);
    float* fsrc1  = (float*)alloc((size_t)NN * 4);
    float* edst1  = (float*)alloc((size_t)NN * 4);
    short* hB1    = (short*)alloc((size_t)NN * 64 * 2);
    float* outp1  = (float*)alloc((size_t)16 * NN * 64 * 4);     // 33.5MB
    float* normp1 = (float*)alloc((size_t)NN * 16 * 4);          // 512KB
    float* h1     = (float*)alloc((size_t)NN * 64 * 4);
    float* z      = (float*)alloc((size_t)NN * 16 * 4);
    float* fsrc2  = (float*)alloc((size_t)NN * 4);
    float* edst2  = (float*)alloc((size_t)NN * 4);
    short* zB     = (short*)alloc((size_t)NN * 16 * 2);
    float* outp2  = (float*)alloc((size_t)16 * NN * 16 * 4);     // 8.4MB
    float* normp2 = (float*)alloc((size_t)NN * 16 * 4);

    hipLaunchKernelGGL(p1_kernel, dim3(NN / 16), dim3(256), 0, stream,
                       x, W1, a1, h, fsrc1, edst1);
    hipLaunchKernelGGL(swizzle_kernel, dim3(2048), dim3(256), 0, stream,
                       h, hB1, 4, 64, NN * 64);
    hipLaunchKernelGGL(att_kernel, dim3(ATT_BLOCKS), dim3(256), 0, stream,
                       adj, fsrc1, edst1, attB, normp1);
    hipLaunchKernelGGL((gemm_kernel<4>), dim3(64, 16), dim3(512), 0, stream,
                       attB, hB1, outp1);
    hipLaunchKernelGGL(r1_kernel, dim3(2048), dim3(256), 0, stream,
                       outp1, normp1, h1);
    hipLaunchKernelGGL(p2_kernel, dim3(32), dim3(256), 0, stream,
                       h1, W2, a2, z, fsrc2, edst2);
    hipLaunchKernelGGL(swizzle_kernel, dim3(512), dim3(256), 0, stream,
                       z, zB, 1, 16, NN * 16);
    hipLaunchKernelGGL(att_kernel, dim3(ATT_BLOCKS), dim3(256), 0, stream,
                       adj, fsrc2, edst2, attB, normp2);
    hipLaunchKernelGGL((gemm_kernel<1>), dim3(64, 16), dim3(512), 0, stream,
                       attB, zB, outp2);
    hipLaunchKernelGGL(r2_kernel, dim3(32), dim3(256), 0, stream,
                       outp2, normp2, out);
}

// Round 9
// 299.481 us; speedup vs baseline: 1.5468x; 1.4353x over previous
//
#include <hip/hip_runtime.h>
#include <hip/hip_bf16.h>
#include <math.h>

typedef __attribute__((ext_vector_type(4))) float f32x4;
typedef __attribute__((ext_vector_type(4))) int   i32x4;
typedef __attribute__((ext_vector_type(8))) short short8;

#define NN 8192
#define LOG2E 1.44269504088896f
#define ATT_BLOCKS 2048

// f32 -> bf16 bits, round-to-nearest-even
__device__ __forceinline__ unsigned f2bfu(float x) {
    unsigned u = __float_as_uint(x);
    u += 0x7FFFu + ((u >> 16) & 1u);
    return u >> 16;
}
__device__ __forceinline__ float expneg(float s) {   // exp(-s)
    return __builtin_amdgcn_exp2f(-LOG2E * s);
}

// ---------------------------------------------------------------------------
// P1: h = x @ W1  [8192,500]@[500,64] with W1 staged in LDS. 512 blocks x
// 16 rows (4 rows/wave). Writes fsrc/edst = exp(-h.a halves).
// ---------------------------------------------------------------------------
#define P1_CHUNK 100
__global__ __launch_bounds__(256) void p1_kernel(
    const float* __restrict__ x, const float* __restrict__ W1,
    const float* __restrict__ a1, float* __restrict__ h,
    float* __restrict__ fsrc, float* __restrict__ edst)
{
    __shared__ float wtile[P1_CHUNK * 64];
    const int lane = threadIdx.x & 63;
    const int w    = threadIdx.x >> 6;
    const int r0   = blockIdx.x * 16 + w * 4;

    float acc[4];
#pragma unroll
    for (int r = 0; r < 4; ++r) acc[r] = 0.f;

    for (int c = 0; c < 5; ++c) {
        const int kb = c * P1_CHUNK;
        __syncthreads();
        for (int idx = threadIdx.x; idx < P1_CHUNK * 64; idx += 256)
            wtile[idx] = W1[kb * 64 + idx];
        __syncthreads();
        for (int kk = 0; kk < P1_CHUNK; kk += 4) {
            float w0 = wtile[(kk + 0) * 64 + lane];
            float w1 = wtile[(kk + 1) * 64 + lane];
            float w2 = wtile[(kk + 2) * 64 + lane];
            float w3 = wtile[(kk + 3) * 64 + lane];
#pragma unroll
            for (int r = 0; r < 4; ++r) {
                f32x4 xv = *(const f32x4*)(x + (size_t)(r0 + r) * 500 + kb + kk);
                acc[r] = fmaf(xv[0], w0, acc[r]);
                acc[r] = fmaf(xv[1], w1, acc[r]);
                acc[r] = fmaf(xv[2], w2, acc[r]);
                acc[r] = fmaf(xv[3], w3, acc[r]);
            }
        }
    }
    float a_s = a1[lane], a_d = a1[64 + lane];
#pragma unroll
    for (int r = 0; r < 4; ++r) {
        h[(size_t)(r0 + r) * 64 + lane] = acc[r];
        float ps = acc[r] * a_s, pd = acc[r] * a_d;
        for (int off = 32; off > 0; off >>= 1) {
            ps += __shfl_down(ps, off); pd += __shfl_down(pd, off);
        }
        if (lane == 0) {
            fsrc[r0 + r] = expneg(ps);
            edst[r0 + r] = expneg(pd);
        }
    }
}

// ---------------------------------------------------------------------------
// Swizzle f32 matrix into bf16 B-fragment order:
// hB[kb][nb][lane][i] = bf16( h[kb*32 + (lane>>4)*8 + i][nb*16 + (lane&15)] )
// ---------------------------------------------------------------------------
__global__ __launch_bounds__(256) void swizzle_kernel(
    const float* __restrict__ h, short* __restrict__ hB,
    int nblk, int ncols, int total)
{
    int tid = blockIdx.x * 256 + threadIdx.x;
    if (tid >= total) return;
    int i  = tid & 7;
    int l  = (tid >> 3) & 63;
    int t2 = tid >> 9;
    int nb = t2 % nblk;
    int kb = t2 / nblk;
    int row = kb * 32 + (l >> 4) * 8 + i;
    int col = nb * 16 + (l & 15);
    float v = h[(size_t)row * ncols + col];
    hB[tid] = (short)f2bfu(v);
}

// ---------------------------------------------------------------------------
// att_kernel v3: line-clean on BOTH sides. Wave = one (mb, kb) 16x32 tile
// per iteration, 16 consecutive kb per wave (mb = wid>>4, kb0 = (wid&15)*16).
// Load layout lane l' = r*4+q: a0 = adj[row=mb*16+r][kb*32+q*4] (4 lanes =
// one FULL 64B line per row), a1 at +16 cols. Compute att = adj*rcp(1+F*E),
// pack bf16, then 8x ds_bpermute (fixed permutation to fragment lanes
// l = g*16+r) -> each wave stores 1KB CONTIGUOUS in fragment order.
// Norm accumulates in-register across the wave's 16 kb; one store at end.
// No LDS arrays, no barriers.
// ---------------------------------------------------------------------------
__global__ __launch_bounds__(256) void att_kernel(
    const float* __restrict__ adj, const float* __restrict__ fsrc,
    const float* __restrict__ edst, short* __restrict__ attB,
    float* __restrict__ normpart)
{
    const int tid  = threadIdx.x;
    const int lane = tid & 63;
    const int wid  = (blockIdx.x * 256 + tid) >> 6;   // 0..8191
    const int mb   = wid >> 4;                        // 0..511
    const int wseg = wid & 15;
    const int kb0  = wseg * 16;

    const int r = lane >> 2;       // load-layout row 0..15
    const int q = lane & 3;        // load-layout col quarter

    const float F_i = fsrc[mb * 16 + r];
    const float* arow = adj + (size_t)(mb * 16 + r) * NN;

    // fragment-lane coordinates (for the permuted store)
    const int fg = lane >> 4;             // g of MY lane as destination
    const int fr = lane & 15;             // r of MY lane as destination
    const int s0 = fr * 4 + (fg & 1) * 2; // source lanes for my fragment
    const int s1 = s0 + 1;
    const bool lowhalf = (fg < 2);

    float nacc = 0.f;

    for (int k = 0; k < 16; ++k) {
        const int kb   = kb0 + k;
        const int col0 = kb * 32;
        // full-line loads: lane covers cols {q*4..+3} and {16+q*4..+3}
        f32x4 a0 = *(const f32x4*)(arow + col0 + q * 4);
        f32x4 a1 = *(const f32x4*)(arow + col0 + 16 + q * 4);
        f32x4 e0 = *(const f32x4*)(edst + col0 + q * 4);
        f32x4 e1 = *(const f32x4*)(edst + col0 + 16 + q * 4);

        float v[8];
#pragma unroll
        for (int t = 0; t < 4; ++t) {
            float sg  = __builtin_amdgcn_rcpf(fmaf(F_i, e0[t], 1.0f));
            float att = sg * a0[t];
            nacc = fmaf(att, att, nacc);
            v[t] = att;
        }
#pragma unroll
        for (int t = 0; t < 4; ++t) {
            float sg  = __builtin_amdgcn_rcpf(fmaf(F_i, e1[t], 1.0f));
            float att = sg * a1[t];
            nacc = fmaf(att, att, nacc);
            v[4 + t] = att;
        }
        // pack: d0 = cols(q*4+0, +1), d1 = (q*4+2, +3), d2/d3 = +16 versions
        int d0 = (int)(f2bfu(v[0]) | (f2bfu(v[1]) << 16));
        int d1 = (int)(f2bfu(v[2]) | (f2bfu(v[3]) << 16));
        int d2 = (int)(f2bfu(v[4]) | (f2bfu(v[5]) << 16));
        int d3 = (int)(f2bfu(v[6]) | (f2bfu(v[7]) << 16));

        // permute to fragment lanes: dst lane (fg,fr) gets cols fg*8..fg*8+7
        int p00 = __shfl(d0, s0, 64), p01 = __shfl(d1, s0, 64);
        int p10 = __shfl(d0, s1, 64), p11 = __shfl(d1, s1, 64);
        int q00 = __shfl(d2, s0, 64), q01 = __shfl(d3, s0, 64);
        int q10 = __shfl(d2, s1, 64), q11 = __shfl(d3, s1, 64);
        i32x4 wv;
        wv[0] = lowhalf ? p00 : q00;
        wv[1] = lowhalf ? p01 : q01;
        wv[2] = lowhalf ? p10 : q10;
        wv[3] = lowhalf ? p11 : q11;
        // contiguous 1KB/wave store in fragment order
        *(i32x4*)(attB + (((size_t)mb * 256 + kb) * 64 + lane) * 8) = wv;
    }

    // norm partial: reduce over q (lanes r*4..r*4+3 hold row r pieces)
    nacc += __shfl_xor(nacc, 1);
    nacc += __shfl_xor(nacc, 2);
    if (q == 0) normpart[(mb * 16 + r) * 16 + wseg] = nacc;
}

// ---------------------------------------------------------------------------
// Skinny GEMM: C_partial[seg] = attB[:, seg-cols] @ Bfrag[seg].
// A-fragments are CONTIGUOUS short8 loads from fragment-ordered attB;
// B-slice staged in LDS once; depth-4 A register prefetch.
// Block = 8 waves x 16 rows = 128 rows. Grid (64, 16).
// ---------------------------------------------------------------------------
template <int NBLK>
__global__ __launch_bounds__(512) void gemm_kernel(
    const short* __restrict__ A, const short* __restrict__ Bfrag,
    float* __restrict__ outp)
{
    __shared__ __align__(16) short Bs[16 * NBLK * 64 * 8];
    const int tid  = threadIdx.x;
    const int lane = tid & 63;
    const int w    = tid >> 6;
    const int seg  = blockIdx.y;
    const int mb   = blockIdx.x * 8 + w;
    const int r    = lane & 15;
    const int g    = lane >> 4;

    {
        const short8* src = (const short8*)(Bfrag) + (size_t)seg * (16 * NBLK * 64);
        short8* dst = (short8*)Bs;
#pragma unroll
        for (int j = 0; j < 2 * NBLK; ++j)
            dst[tid + 512 * j] = src[tid + 512 * j];
    }
    __syncthreads();

    const short8* Ap = (const short8*)(A) + ((size_t)mb * 256 + seg * 16) * 64 + lane;

    f32x4 acc[NBLK];
#pragma unroll
    for (int nb = 0; nb < NBLK; ++nb) acc[nb] = (f32x4){0.f, 0.f, 0.f, 0.f};

    auto compute = [&](int k, short8 av) {
#pragma unroll
        for (int nb = 0; nb < NBLK; ++nb) {
            short8 bf = *(const short8*)&Bs[((k * NBLK + nb) * 64 + lane) * 8];
            acc[nb] = __builtin_amdgcn_mfma_f32_16x16x32_bf16(av, bf, acc[nb], 0, 0, 0);
        }
    };

    short8 A0 = Ap[0 * 64], A1 = Ap[1 * 64], A2 = Ap[2 * 64], A3 = Ap[3 * 64];
#pragma unroll
    for (int k = 0; k < 16; k += 4) {
        short8 N0 = A0, N1 = A1, N2 = A2, N3 = A3;
        if (k + 4 < 16) {
            N0 = Ap[(k + 4) * 64]; N1 = Ap[(k + 5) * 64];
            N2 = Ap[(k + 6) * 64]; N3 = Ap[(k + 7) * 64];
        }
        compute(k + 0, A0);
        compute(k + 1, A1);
        compute(k + 2, A2);
        compute(k + 3, A3);
        A0 = N0; A1 = N1; A2 = N2; A3 = N3;
    }

    const int F = NBLK * 16;
#pragma unroll
    for (int nb = 0; nb < NBLK; ++nb)
#pragma unroll
        for (int rr = 0; rr < 4; ++rr)
            outp[((size_t)seg * NN + mb * 16 + g * 4 + rr) * F + nb * 16 + r]
                = acc[nb][rr];
}

// ---------------------------------------------------------------------------
// R1: h1[i][f] = sum_seg outp1 / (sqrt(sum_p normpart1[i][p]) + 1e-10)
// ---------------------------------------------------------------------------
__global__ __launch_bounds__(256) void r1_kernel(
    const float* __restrict__ outp, const float* __restrict__ normpart,
    float* __restrict__ h1)
{
    int tid = blockIdx.x * 256 + threadIdx.x;
    int i = tid >> 6, f = tid & 63;
    float s = 0.f;
#pragma unroll
    for (int sg = 0; sg < 16; ++sg)
        s += outp[((size_t)sg * NN + i) * 64 + f];
    float n = 0.f;
#pragma unroll
    for (int p = 0; p < 16; ++p) n += normpart[i * 16 + p];
    h1[tid] = s / (sqrtf(n) + 1e-10f);
}

// ---------------------------------------------------------------------------
// P2: z = h1 @ W2 (padded to 16 cols), fsrc2/edst2 = exp(-z . a2 halves)
// ---------------------------------------------------------------------------
__global__ __launch_bounds__(256) void p2_kernel(
    const float* __restrict__ h1, const float* __restrict__ W2,
    const float* __restrict__ a2, float* __restrict__ z,
    float* __restrict__ fsrc2, float* __restrict__ edst2)
{
    int i = blockIdx.x * 256 + threadIdx.x;
    if (i >= NN) return;
    float zz[10];
#pragma unroll
    for (int c = 0; c < 10; ++c) zz[c] = 0.f;
    for (int f = 0; f < 64; ++f) {
        float hv = h1[(size_t)i * 64 + f];
#pragma unroll
        for (int c = 0; c < 10; ++c) zz[c] = fmaf(hv, W2[f * 10 + c], zz[c]);
    }
    float s1 = 0.f, s2 = 0.f;
#pragma unroll
    for (int c = 0; c < 10; ++c) {
        s1 = fmaf(zz[c], a2[c], s1);
        s2 = fmaf(zz[c], a2[10 + c], s2);
        z[(size_t)i * 16 + c] = zz[c];
    }
#pragma unroll
    for (int c = 10; c < 16; ++c) z[(size_t)i * 16 + c] = 0.f;
    fsrc2[i] = expneg(s1);
    edst2[i] = expneg(s2);
}

// ---------------------------------------------------------------------------
// R2: h2 = partials/norm, then log_softmax over 10 classes -> d_out
// ---------------------------------------------------------------------------
__global__ __launch_bounds__(256) void r2_kernel(
    const float* __restrict__ outp, const float* __restrict__ normpart,
    float* __restrict__ out)
{
    int i = blockIdx.x * 256 + threadIdx.x;
    if (i >= NN) return;
    float n = 0.f;
#pragma unroll
    for (int p = 0; p < 16; ++p) n += normpart[i * 16 + p];
    float inv = 1.0f / (sqrtf(n) + 1e-10f);
    float v[10];
    float m = -1e30f;
#pragma unroll
    for (int c = 0; c < 10; ++c) {
        float s = 0.f;
#pragma unroll
        for (int sg = 0; sg < 16; ++sg)
            s += outp[((size_t)sg * NN + i) * 16 + c];
        v[c] = s * inv;
        m = fmaxf(m, v[c]);
    }
    float es = 0.f;
#pragma unroll
    for (int c = 0; c < 10; ++c) es += expf(v[c] - m);
    float lse = m + logf(es);
#pragma unroll
    for (int c = 0; c < 10; ++c) out[(size_t)i * 10 + c] = v[c] - lse;
}

extern "C" void kernel_launch(void* const* d_in, const int* in_sizes, int n_in,
                              void* d_out, int out_size, void* d_ws, size_t ws_size,
                              hipStream_t stream)
{
    const float* x   = (const float*)d_in[0];
    const float* adj = (const float*)d_in[1];
    const float* W1  = (const float*)d_in[2];
    const float* a1  = (const float*)d_in[3];
    const float* W2  = (const float*)d_in[4];
    const float* a2  = (const float*)d_in[5];
    float* out = (float*)d_out;

    char* ws = (char*)d_ws;
    size_t off = 0;
    auto alloc = [&](size_t bytes) -> void* {
        void* p = ws + off;
        off += (bytes + 255) & ~(size_t)255;
        return p;
    };
    short* attB   = (short*)alloc((size_t)NN * NN * 2);          // 134MB (reused layer 2)
    float* h      = (float*)alloc((size_t)NN * 64 * 4);
    float* fsrc1  = (float*)alloc((size_t)NN * 4);
    float* edst1  = (float*)alloc((size_t)NN * 4);
    short* hB1    = (short*)alloc((size_t)NN * 64 * 2);
    float* outp1  = (float*)alloc((size_t)16 * NN * 64 * 4);     // 33.5MB
    float* normp1 = (float*)alloc((size_t)NN * 16 * 4);          // 512KB
    float* h1     = (float*)alloc((size_t)NN * 64 * 4);
    float* z      = (float*)alloc((size_t)NN * 16 * 4);
    float* fsrc2  = (float*)alloc((size_t)NN * 4);
    float* edst2  = (float*)alloc((size_t)NN * 4);
    short* zB     = (short*)alloc((size_t)NN * 16 * 2);
    float* outp2  = (float*)alloc((size_t)16 * NN * 16 * 4);     // 8.4MB
    float* normp2 = (float*)alloc((size_t)NN * 16 * 4);

    hipLaunchKernelGGL(p1_kernel, dim3(NN / 16), dim3(256), 0, stream,
                       x, W1, a1, h, fsrc1, edst1);
    hipLaunchKernelGGL(swizzle_kernel, dim3(2048), dim3(256), 0, stream,
                       h, hB1, 4, 64, NN * 64);
    hipLaunchKernelGGL(att_kernel, dim3(ATT_BLOCKS), dim3(256), 0, stream,
                       adj, fsrc1, edst1, attB, normp1);
    hipLaunchKernelGGL((gemm_kernel<4>), dim3(64, 16), dim3(512), 0, stream,
                       attB, hB1, outp1);
    hipLaunchKernelGGL(r1_kernel, dim3(2048), dim3(256), 0, stream,
                       outp1, normp1, h1);
    hipLaunchKernelGGL(p2_kernel, dim3(32), dim3(256), 0, stream,
                       h1, W2, a2, z, fsrc2, edst2);
    hipLaunchKernelGGL(swizzle_kernel, dim3(512), dim3(256), 0, stream,
                       z, zB, 1, 16, NN * 16);
    hipLaunchKernelGGL(att_kernel, dim3(ATT_BLOCKS), dim3(256), 0, stream,
                       adj, fsrc2, edst2, attB, normp2);
    hipLaunchKernelGGL((gemm_kernel<1>), dim3(64, 16), dim3(512), 0, stream,
                       attB, zB, outp2);
    hipLaunchKernelGGL(r2_kernel, dim3(32), dim3(256), 0, stream,
                       outp2, normp2, out);
}

// Round 10
// 209.310 us; speedup vs baseline: 2.2132x; 1.4308x over previous
//
#include <hip/hip_runtime.h>
#include <hip/hip_bf16.h>
#include <math.h>

typedef __attribute__((ext_vector_type(4))) float f32x4;
typedef __attribute__((ext_vector_type(4))) int   i32x4;
typedef __attribute__((ext_vector_type(8))) short short8;

#define NN 8192
#define LOG2E 1.44269504088896f

// f32 -> bf16 bits, round-to-nearest-even
__device__ __forceinline__ unsigned f2bfu(float x) {
    unsigned u = __float_as_uint(x);
    u += 0x7FFFu + ((u >> 16) & 1u);
    return u >> 16;
}
__device__ __forceinline__ float expneg(float s) {   // exp(-s)
    return __builtin_amdgcn_exp2f(-LOG2E * s);
}

// ---------------------------------------------------------------------------
// P1: h = x @ W1  [8192,500]@[500,64] with W1 staged in LDS. 512 blocks x
// 16 rows (4 rows/wave). Writes fsrc/edst = exp(-h.a halves).
// ---------------------------------------------------------------------------
#define P1_CHUNK 100
__global__ __launch_bounds__(256) void p1_kernel(
    const float* __restrict__ x, const float* __restrict__ W1,
    const float* __restrict__ a1, float* __restrict__ h,
    float* __restrict__ fsrc, float* __restrict__ edst)
{
    __shared__ float wtile[P1_CHUNK * 64];
    const int lane = threadIdx.x & 63;
    const int w    = threadIdx.x >> 6;
    const int r0   = blockIdx.x * 16 + w * 4;

    float acc[4];
#pragma unroll
    for (int r = 0; r < 4; ++r) acc[r] = 0.f;

    for (int c = 0; c < 5; ++c) {
        const int kb = c * P1_CHUNK;
        __syncthreads();
        for (int idx = threadIdx.x; idx < P1_CHUNK * 64; idx += 256)
            wtile[idx] = W1[kb * 64 + idx];
        __syncthreads();
        for (int kk = 0; kk < P1_CHUNK; kk += 4) {
            float w0 = wtile[(kk + 0) * 64 + lane];
            float w1 = wtile[(kk + 1) * 64 + lane];
            float w2 = wtile[(kk + 2) * 64 + lane];
            float w3 = wtile[(kk + 3) * 64 + lane];
#pragma unroll
            for (int r = 0; r < 4; ++r) {
                f32x4 xv = *(const f32x4*)(x + (size_t)(r0 + r) * 500 + kb + kk);
                acc[r] = fmaf(xv[0], w0, acc[r]);
                acc[r] = fmaf(xv[1], w1, acc[r]);
                acc[r] = fmaf(xv[2], w2, acc[r]);
                acc[r] = fmaf(xv[3], w3, acc[r]);
            }
        }
    }
    float a_s = a1[lane], a_d = a1[64 + lane];
#pragma unroll
    for (int r = 0; r < 4; ++r) {
        h[(size_t)(r0 + r) * 64 + lane] = acc[r];
        float ps = acc[r] * a_s, pd = acc[r] * a_d;
        for (int off = 32; off > 0; off >>= 1) {
            ps += __shfl_down(ps, off); pd += __shfl_down(pd, off);
        }
        if (lane == 0) {
            fsrc[r0 + r] = expneg(ps);
            edst[r0 + r] = expneg(pd);
        }
    }
}

// ---------------------------------------------------------------------------
// Swizzle f32 matrix into bf16 B-fragment order:
// hB[kb][nb][lane][i] = bf16( h[kb*32 + (lane>>4)*8 + i][nb*16 + (lane&15)] )
// ---------------------------------------------------------------------------
__global__ __launch_bounds__(256) void swizzle_kernel(
    const float* __restrict__ h, short* __restrict__ hB,
    int nblk, int ncols, int total)
{
    int tid = blockIdx.x * 256 + threadIdx.x;
    if (tid >= total) return;
    int i  = tid & 7;
    int l  = (tid >> 3) & 63;
    int t2 = tid >> 9;
    int nb = t2 % nblk;
    int kb = t2 / nblk;
    int row = kb * 32 + (l >> 4) * 8 + i;
    int col = nb * 16 + (l & 15);
    float v = h[(size_t)row * ncols + col];
    hB[tid] = (short)f2bfu(v);
}

// ---------------------------------------------------------------------------
// FUSED GAT layer. Block = 8 waves x 512 thr; wave owns mb = bx*8+w (16 rows)
// x seg (16 k-blocks of 32 cols). B-slice staged in LDS once (one barrier).
// K-loop (all in-register, NO stores, no other VMEM):
//   - clean line loads: lane l'=(r*4+q) reads adj[row=mb*16+r][kb*32+q*4(+16)]
//     (4 lanes = one full 64B line per row)
//   - att = adj * rcp(1 + F_i*E_j); nacc += att^2
//   - pack bf16, 8x shfl + cndmask -> lane holds its MFMA A-fragment
//   - 4 (or 1) MFMA vs LDS B-fragments
// Epilogue: norm partial -> normpart[row][seg]; C -> outp[seg][row][F].
// ---------------------------------------------------------------------------
template <int NBLK>
__global__ __launch_bounds__(512) void fused_kernel(
    const float* __restrict__ adj, const float* __restrict__ fsrc,
    const float* __restrict__ edst, const short* __restrict__ Bfrag,
    float* __restrict__ outp, float* __restrict__ normpart)
{
    __shared__ __align__(16) short Bs[16 * NBLK * 64 * 8];  // 64KB (NBLK=4) / 16KB
    const int tid  = threadIdx.x;
    const int lane = tid & 63;
    const int w    = tid >> 6;
    const int seg  = blockIdx.y;
    const int mb   = blockIdx.x * 8 + w;

    // stage B-slice (fragment order, contiguous)
    {
        const short8* src = (const short8*)(Bfrag) + (size_t)seg * (16 * NBLK * 64);
        short8* dst = (short8*)Bs;
#pragma unroll
        for (int j = 0; j < 2 * NBLK; ++j)
            dst[tid + 512 * j] = src[tid + 512 * j];
    }
    __syncthreads();

    const int r = lane >> 2;       // load-layout row 0..15
    const int q = lane & 3;        // load-layout col quarter

    const float F_i = fsrc[mb * 16 + r];
    const float* arow = adj + (size_t)(mb * 16 + r) * NN;

    // fragment-lane coordinates (destination of the permute)
    const int fg = lane >> 4;
    const int fr = lane & 15;
    const int s0 = fr * 4 + (fg & 1) * 2;
    const int s1 = s0 + 1;
    const bool lowhalf = (fg < 2);

    f32x4 acc[NBLK];
#pragma unroll
    for (int nb = 0; nb < NBLK; ++nb) acc[nb] = (f32x4){0.f, 0.f, 0.f, 0.f};
    float nacc = 0.f;

    for (int k = 0; k < 16; ++k) {
        const int col0 = (seg * 16 + k) * 32;
        f32x4 a0 = *(const f32x4*)(arow + col0 + q * 4);
        f32x4 a1 = *(const f32x4*)(arow + col0 + 16 + q * 4);
        f32x4 e0 = *(const f32x4*)(edst + col0 + q * 4);
        f32x4 e1 = *(const f32x4*)(edst + col0 + 16 + q * 4);

        float v[8];
#pragma unroll
        for (int t = 0; t < 4; ++t) {
            float sg  = __builtin_amdgcn_rcpf(fmaf(F_i, e0[t], 1.0f));
            float att = sg * a0[t];
            nacc = fmaf(att, att, nacc);
            v[t] = att;
        }
#pragma unroll
        for (int t = 0; t < 4; ++t) {
            float sg  = __builtin_amdgcn_rcpf(fmaf(F_i, e1[t], 1.0f));
            float att = sg * a1[t];
            nacc = fmaf(att, att, nacc);
            v[4 + t] = att;
        }
        int d0 = (int)(f2bfu(v[0]) | (f2bfu(v[1]) << 16));
        int d1 = (int)(f2bfu(v[2]) | (f2bfu(v[3]) << 16));
        int d2 = (int)(f2bfu(v[4]) | (f2bfu(v[5]) << 16));
        int d3 = (int)(f2bfu(v[6]) | (f2bfu(v[7]) << 16));

        int p00 = __shfl(d0, s0, 64), p01 = __shfl(d1, s0, 64);
        int p10 = __shfl(d0, s1, 64), p11 = __shfl(d1, s1, 64);
        int q00 = __shfl(d2, s0, 64), q01 = __shfl(d3, s0, 64);
        int q10 = __shfl(d2, s1, 64), q11 = __shfl(d3, s1, 64);
        i32x4 wv;
        wv[0] = lowhalf ? p00 : q00;
        wv[1] = lowhalf ? p01 : q01;
        wv[2] = lowhalf ? p10 : q10;
        wv[3] = lowhalf ? p11 : q11;
        short8 af = *(short8*)&wv;

#pragma unroll
        for (int nb = 0; nb < NBLK; ++nb) {
            short8 bf = *(const short8*)&Bs[((k * NBLK + nb) * 64 + lane) * 8];
            acc[nb] = __builtin_amdgcn_mfma_f32_16x16x32_bf16(af, bf, acc[nb], 0, 0, 0);
        }
    }

    // norm partial: lanes r*4..r*4+3 hold row r pieces
    nacc += __shfl_xor(nacc, 1);
    nacc += __shfl_xor(nacc, 2);
    if (q == 0) normpart[(mb * 16 + r) * 16 + seg] = nacc;

    // C/D: col = lane&15, row = (lane>>4)*4 + rr
    constexpr int F = NBLK * 16;
#pragma unroll
    for (int nb = 0; nb < NBLK; ++nb)
#pragma unroll
        for (int rr = 0; rr < 4; ++rr)
            outp[((size_t)seg * NN + mb * 16 + fg * 4 + rr) * F + nb * 16 + fr]
                = acc[nb][rr];
}

// ---------------------------------------------------------------------------
// R1: h1[i][f] = sum_seg outp1 / (sqrt(sum_p normpart1[i][p]) + 1e-10)
// ---------------------------------------------------------------------------
__global__ __launch_bounds__(256) void r1_kernel(
    const float* __restrict__ outp, const float* __restrict__ normpart,
    float* __restrict__ h1)
{
    int tid = blockIdx.x * 256 + threadIdx.x;
    int i = tid >> 6, f = tid & 63;
    float s = 0.f;
#pragma unroll
    for (int sg = 0; sg < 16; ++sg)
        s += outp[((size_t)sg * NN + i) * 64 + f];
    float n = 0.f;
#pragma unroll
    for (int p = 0; p < 16; ++p) n += normpart[i * 16 + p];
    h1[tid] = s / (sqrtf(n) + 1e-10f);
}

// ---------------------------------------------------------------------------
// P2: z = h1 @ W2 (padded to 16 cols), fsrc2/edst2 = exp(-z . a2 halves)
// ---------------------------------------------------------------------------
__global__ __launch_bounds__(256) void p2_kernel(
    const float* __restrict__ h1, const float* __restrict__ W2,
    const float* __restrict__ a2, float* __restrict__ z,
    float* __restrict__ fsrc2, float* __restrict__ edst2)
{
    int i = blockIdx.x * 256 + threadIdx.x;
    if (i >= NN) return;
    float zz[10];
#pragma unroll
    for (int c = 0; c < 10; ++c) zz[c] = 0.f;
    for (int f = 0; f < 64; ++f) {
        float hv = h1[(size_t)i * 64 + f];
#pragma unroll
        for (int c = 0; c < 10; ++c) zz[c] = fmaf(hv, W2[f * 10 + c], zz[c]);
    }
    float s1 = 0.f, s2 = 0.f;
#pragma unroll
    for (int c = 0; c < 10; ++c) {
        s1 = fmaf(zz[c], a2[c], s1);
        s2 = fmaf(zz[c], a2[10 + c], s2);
        z[(size_t)i * 16 + c] = zz[c];
    }
#pragma unroll
    for (int c = 10; c < 16; ++c) z[(size_t)i * 16 + c] = 0.f;
    fsrc2[i] = expneg(s1);
    edst2[i] = expneg(s2);
}

// ---------------------------------------------------------------------------
// R2: h2 = partials/norm, then log_softmax over 10 classes -> d_out
// ---------------------------------------------------------------------------
__global__ __launch_bounds__(256) void r2_kernel(
    const float* __restrict__ outp, const float* __restrict__ normpart,
    float* __restrict__ out)
{
    int i = blockIdx.x * 256 + threadIdx.x;
    if (i >= NN) return;
    float n = 0.f;
#pragma unroll
    for (int p = 0; p < 16; ++p) n += normpart[i * 16 + p];
    float inv = 1.0f / (sqrtf(n) + 1e-10f);
    float v[10];
    float m = -1e30f;
#pragma unroll
    for (int c = 0; c < 10; ++c) {
        float s = 0.f;
#pragma unroll
        for (int sg = 0; sg < 16; ++sg)
            s += outp[((size_t)sg * NN + i) * 16 + c];
        v[c] = s * inv;
        m = fmaxf(m, v[c]);
    }
    float es = 0.f;
#pragma unroll
    for (int c = 0; c < 10; ++c) es += expf(v[c] - m);
    float lse = m + logf(es);
#pragma unroll
    for (int c = 0; c < 10; ++c) out[(size_t)i * 10 + c] = v[c] - lse;
}

extern "C" void kernel_launch(void* const* d_in, const int* in_sizes, int n_in,
                              void* d_out, int out_size, void* d_ws, size_t ws_size,
                              hipStream_t stream)
{
    const float* x   = (const float*)d_in[0];
    const float* adj = (const float*)d_in[1];
    const float* W1  = (const float*)d_in[2];
    const float* a1  = (const float*)d_in[3];
    const float* W2  = (const float*)d_in[4];
    const float* a2  = (const float*)d_in[5];
    float* out = (float*)d_out;

    char* ws = (char*)d_ws;
    size_t off = 0;
    auto alloc = [&](size_t bytes) -> void* {
        void* p = ws + off;
        off += (bytes + 255) & ~(size_t)255;
        return p;
    };
    float* h      = (float*)alloc((size_t)NN * 64 * 4);
    float* fsrc1  = (float*)alloc((size_t)NN * 4);
    float* edst1  = (float*)alloc((size_t)NN * 4);
    short* hB1    = (short*)alloc((size_t)NN * 64 * 2);
    float* outp1  = (float*)alloc((size_t)16 * NN * 64 * 4);     // 33.5MB
    float* normp1 = (float*)alloc((size_t)NN * 16 * 4);          // 512KB
    float* h1     = (float*)alloc((size_t)NN * 64 * 4);
    float* z      = (float*)alloc((size_t)NN * 16 * 4);
    float* fsrc2  = (float*)alloc((size_t)NN * 4);
    float* edst2  = (float*)alloc((size_t)NN * 4);
    short* zB     = (short*)alloc((size_t)NN * 16 * 2);
    float* outp2  = (float*)alloc((size_t)16 * NN * 16 * 4);     // 8.4MB
    float* normp2 = (float*)alloc((size_t)NN * 16 * 4);

    hipLaunchKernelGGL(p1_kernel, dim3(NN / 16), dim3(256), 0, stream,
                       x, W1, a1, h, fsrc1, edst1);
    hipLaunchKernelGGL(swizzle_kernel, dim3(2048), dim3(256), 0, stream,
                       h, hB1, 4, 64, NN * 64);
    hipLaunchKernelGGL((fused_kernel<4>), dim3(64, 16), dim3(512), 0, stream,
                       adj, fsrc1, edst1, hB1, outp1, normp1);
    hipLaunchKernelGGL(r1_kernel, dim3(2048), dim3(256), 0, stream,
                       outp1, normp1, h1);
    hipLaunchKernelGGL(p2_kernel, dim3(32), dim3(256), 0, stream,
                       h1, W2, a2, z, fsrc2, edst2);
    hipLaunchKernelGGL(swizzle_kernel, dim3(512), dim3(256), 0, stream,
                       z, zB, 1, 16, NN * 16);
    hipLaunchKernelGGL((fused_kernel<1>), dim3(64, 16), dim3(512), 0, stream,
                       adj, fsrc2, edst2, zB, outp2, normp2);
    hipLaunchKernelGGL(r2_kernel, dim3(32), dim3(256), 0, stream,
                       outp2, normp2, out);
}